// Round 12
// baseline (803.052 us; speedup 1.0000x reference)
//
#include <hip/hip_runtime.h>
#include <math.h>

// Problem constants
constexpr int Dc = 128;   // channels
constexpr int Kc = 512;   // codebook entries
constexpr int Bc = 8;     // batch

// ---------------------------------------------------------------------------
// LDS-tiled layer kernel: conv (ISADD=0) or AdderNet L1 (ISADD=1).
// Block = NW waves; KSPLIT wave-groups of NWG=NW/KSPLIT waves. Group g
// computes the block's couts over channels [g*CIN/KSPLIT, (g+1)*CIN/KSPLIT)
// at full COBW; partials combined via round-robin LDS scratch.
// R24: NARROW BLOCKS — NW=4 (4-wave blocks), grid doubled, per-wave economics
// (COBW/CH-per-group/chunk count) unchanged. Rationale: measured occupancy
// ~52% vs 100% static cap at NW=8; hypothesis = barrier convoy width (8-wave
// __syncthreads stalls coarsely; 8 narrow blocks/CU fill each other's gaps).
// Lever ledger (measured): K-split x2 GOOD (R16); streaming 1x1 GOOD (R18);
// VQ e2-fuse GOOD (R21); occupancy-split of latency-bound tails GOOD (R22:
// -45us); chl unroll-2 kept (R22). COBW growth DEAD (R17); PW growth DEAD
// (R19); chunk growth DEAD (R20); dbuf DEAD (R13). R14: never trade COBW
// for occupancy.
//
// IT: 0 none, 1 relu, 2 relu(bn) with itG/itB
// EPI (val = -acc adder / acc conv): 1 relu(bn_o(val)); 2 res+val;
//   3 bn_r(res)+val; 5 relu(val); 6 bn_o(bn_r(res)+val)
template<int ISADD, int K, int STRIDE, int PAD, int IT, int EPI, int CIN, int CH,
         int PW, int OUT_ROWS, int WOUT, int WIN, int HIN, int HOUT, int COBW,
         int NW, int KSPLIT>
__global__ __launch_bounds__(NW * 64)
void lds_layer(const float* __restrict__ x, const float* __restrict__ w,
               const float* __restrict__ bias,
               const float* __restrict__ itG, const float* __restrict__ itB,
               const float* __restrict__ res,
               const float* __restrict__ rG, const float* __restrict__ rB,
               const float* __restrict__ oG, const float* __restrict__ oB,
               float* __restrict__ out) {
  constexpr int BT = NW * 64;
  constexpr int NWG = NW / KSPLIT;            // waves per K-group
  constexpr int CINW = CIN / KSPLIT;          // channels per K-group
  constexpr int CHS = KSPLIT * CH;            // channels staged per chunk iter
  constexpr int KK = K * K;
  constexpr int SPAN = (PW - 1) * STRIDE + K;
  constexpr int IN_ROWS = (OUT_ROWS - 1) * STRIDE + K;
  constexpr int WPAD = (WOUT - 1) * STRIDE + K;
  constexpr int WLDS = (WPAD + 3) & ~3;       // mult of 4: aligned vector reads
  constexpr int PGW = WOUT / PW;
  static_assert(OUT_ROWS * PGW == 64, "one wave covers the pixel tile");
  static_assert(NW % KSPLIT == 0 && CIN % KSPLIT == 0 && CINW % CH == 0, "split");
  static_assert(KSPLIT == 1 ||
                NWG * 64 * PW * COBW <= CHS * IN_ROWS * WLDS, "scratch fits");
  constexpr int NBAND = HOUT / OUT_ROWS;
  constexpr int W4 = WIN / 4;
  constexpr int NELEM4 = CHS * IN_ROWS * W4;
  constexpr int NIT4 = (NELEM4 + BT - 1) / BT;
  constexpr bool EXACT = (NELEM4 % BT) == 0;
  const float r15 = rsqrtf(1.0f + 1e-5f);

  __shared__ alignas(16) float lds[CHS][IN_ROWS][WLDS];

  int tid = threadIdx.x;
  int gb = blockIdx.x;
  // XCD swizzle: cg outermost -> all channel-groups of a band share an XCD L2.
  int cg = gb / (Bc * NBAND);
  int rem = gb % (Bc * NBAND);
  int band = rem % NBAND;
  int b = rem / NBAND;
  int wv = __builtin_amdgcn_readfirstlane(tid >> 6);
  int lane = tid & 63;
  int grp = wv / NWG;                          // K-group of this wave
  int wloc = wv % NWG;
  int co0 = cg * (NWG * COBW) + wloc * COBW;
  int pr = lane / PGW, pc = lane % PGW;
  int oh = band * OUT_ROWS + pr;
  int ow0 = pc * PW;
  int yi0 = band * OUT_ROWS * STRIDE - PAD;

  // zero LDS once: pad columns stay zero forever
  for (int e = tid; e < CHS * IN_ROWS * WLDS; e += BT) ((float*)lds)[e] = 0.f;

  float acc[PW][COBW];
#pragma unroll
  for (int p = 0; p < PW; ++p)
#pragma unroll
    for (int j = 0; j < COBW; ++j)
      acc[p][j] = (ISADD || grp != 0) ? 0.f : bias[co0 + j];

  const float* xb = x + (long)b * CIN * HIN * WIN;
  float4 rbuf[NIT4];

  // stage chunk cc: tile channel ch2 (<CHS) <- global channel
  //   gc = cc + (ch2 % CH) + (ch2 / CH) * CINW   (group-interleaved slices)
  auto stage = [&](int cc) {
#pragma unroll
    for (int it = 0; it < NIT4; ++it) {
      int e = it * BT + tid;
      if (!EXACT && e >= NELEM4) break;
      int c4 = e % W4;
      int r = (e / W4) % IN_ROWS;
      int ch2 = e / (W4 * IN_ROWS);
      int gc = cc + (ch2 % CH) + (ch2 / CH) * CINW;
      int yi = yi0 + r;
      float4 v = make_float4(0.f, 0.f, 0.f, 0.f);
      if (yi >= 0 && yi < HIN) {
        v = *(const float4*)&xb[((long)gc * HIN + yi) * WIN + 4 * c4];
        if (IT == 1) {
          v.x = fmaxf(v.x, 0.f); v.y = fmaxf(v.y, 0.f);
          v.z = fmaxf(v.z, 0.f); v.w = fmaxf(v.w, 0.f);
        }
        if (IT == 2) {
          float sc = itG[gc] * r15, bc = itB[gc];
          v.x = fmaxf(fmaf(v.x, sc, bc), 0.f);
          v.y = fmaxf(fmaf(v.y, sc, bc), 0.f);
          v.z = fmaxf(fmaf(v.z, sc, bc), 0.f);
          v.w = fmaxf(fmaf(v.w, sc, bc), 0.f);
        }
      }
      rbuf[it] = v;
    }
  };
  auto towrite = [&]() {
#pragma unroll
    for (int it = 0; it < NIT4; ++it) {
      int e = it * BT + tid;
      if (!EXACT && e >= NELEM4) break;
      int c4 = e % W4;
      int r = (e / W4) % IN_ROWS;
      int ch2 = e / (W4 * IN_ROWS);
      float* p = &lds[ch2][r][4 * c4 + PAD];
      float4 v = rbuf[it];
      p[0] = v.x; p[1] = v.y; p[2] = v.z; p[3] = v.w;
    }
  };

  stage(0);
  for (int cc = 0; cc < CINW; cc += CH) {
    __syncthreads();           // previous compute done before LDS overwrite
    towrite();
    __syncthreads();           // all writes visible
    if (cc + CH < CINW) stage(cc + CH);   // loads overlap compute below
#pragma unroll 2
    for (int chl = 0; chl < CH; ++chl) {
      float vbuf[K][SPAN];
#pragma unroll
      for (int kh = 0; kh < K; ++kh) {
        const float* rp0 = &lds[grp * CH + chl][pr * STRIDE + kh][ow0 * STRIDE];
        if constexpr (SPAN == 6 && (PW * STRIDE) % 4 == 0) {
          float4 a = *(const float4*)rp0;            // 16B aligned: col=4*pc
          float2 c2 = *(const float2*)(rp0 + 4);
          vbuf[kh][0] = a.x; vbuf[kh][1] = a.y; vbuf[kh][2] = a.z;
          vbuf[kh][3] = a.w; vbuf[kh][4] = c2.x; vbuf[kh][5] = c2.y;
        } else if constexpr (SPAN == 4 && (PW * STRIDE) % 2 == 0) {
          float2 a = *(const float2*)rp0;            // 8B aligned: col=2*pc
          float2 c2 = *(const float2*)(rp0 + 2);
          vbuf[kh][0] = a.x; vbuf[kh][1] = a.y;
          vbuf[kh][2] = c2.x; vbuf[kh][3] = c2.y;
        } else if constexpr (SPAN == 2 && (PW * STRIDE) % 2 == 0) {
          float2 a = *(const float2*)rp0;
          vbuf[kh][0] = a.x; vbuf[kh][1] = a.y;
        } else {
#pragma unroll
          for (int s = 0; s < SPAN; ++s) vbuf[kh][s] = rp0[s];
        }
      }
      const float* wc = w + ((long)co0 * CIN + (grp * CINW + cc + chl)) * KK;
#pragma unroll
      for (int kh = 0; kh < K; ++kh)
#pragma unroll
        for (int kw = 0; kw < K; ++kw)
#pragma unroll
          for (int j = 0; j < COBW; ++j) {
            float ww = wc[(long)j * CIN * KK + kh * K + kw];
#pragma unroll
            for (int p = 0; p < PW; ++p) {
              float v = vbuf[kh][p * STRIDE + kw];
              if (ISADD) acc[p][j] += fabsf(v - ww);
              else       acc[p][j] = fmaf(v, ww, acc[p][j]);
            }
          }
    }
  }

  // ---- K-split combine: round-robin, group g -> group 0 via LDS scratch ----
  if constexpr (KSPLIT >= 2) {
    float* scr = (float*)lds;
    int sb = (wloc * 64 + lane) * (PW * COBW);
#pragma unroll
    for (int g = 1; g < KSPLIT; ++g) {
      __syncthreads();                     // tile/scratch dead or consumed
      if (grp == g) {
#pragma unroll
        for (int p = 0; p < PW; ++p)
#pragma unroll
          for (int j = 0; j < COBW; ++j) scr[sb + p * COBW + j] = acc[p][j];
      }
      __syncthreads();
      if (grp == 0) {
#pragma unroll
        for (int p = 0; p < PW; ++p)
#pragma unroll
          for (int j = 0; j < COBW; ++j) acc[p][j] += scr[sb + p * COBW + j];
      }
    }
    if (grp != 0) return;                  // non-root groups done
  }

  // ---- epilogue ----
  long obase = ((long)(b * Dc + co0) * HOUT + oh) * WOUT + ow0;
  float* ob = out + obase;
  const float* rp = (EPI == 2 || EPI == 3 || EPI == 6) ? res + obase : nullptr;
  constexpr long hw = (long)HOUT * WOUT;
#pragma unroll
  for (int j = 0; j < COBW; ++j) {
    float og = 0.f, obb = 0.f, rg = 0.f, rbb = 0.f;
    if (EPI == 1 || EPI == 6) { og = oG[co0 + j] * r15; obb = oB[co0 + j]; }
    if (EPI == 3 || EPI == 6) { rg = rG[co0 + j] * r15; rbb = rB[co0 + j]; }
#pragma unroll
    for (int p = 0; p < PW; ++p) {
      float val = ISADD ? -acc[p][j] : acc[p][j];
      if (EPI == 1) val = fmaxf(fmaf(val, og, obb), 0.f);
      if (EPI == 2) val = rp[j * hw + p] + val;
      if (EPI == 3) val = fmaf(rp[j * hw + p], rg, rbb) + val;
      if (EPI == 5) val = fmaxf(val, 0.f);
      if (EPI == 6) val = fmaf(fmaf(rp[j * hw + p], rg, rbb) + val, og, obb);
      ob[j * hw + p] = val;
    }
  }
}

// ---------------------------------------------------------------------------
// R18: streaming 1x1 layer — no staging LDS, no chunk barriers (FROZEN).
template<int ISADD, int EPI, int COBW>
__global__ __launch_bounds__(256)
void pw1x1(const float* __restrict__ x, const float* __restrict__ w,
           const float* __restrict__ bias,
           const float* __restrict__ res,
           const float* __restrict__ rG, const float* __restrict__ rB,
           const float* __restrict__ oG, const float* __restrict__ oB,
           float* __restrict__ out) {
  constexpr int HW = 1024;          // 32x32
  constexpr int CIN = Dc;
  constexpr int KS = 4;             // waves per block = channel segments
  constexpr int CSEG = CIN / KS;    // 32
  constexpr int PXB = 128;          // pixels per block (2 per lane)
  constexpr int NPG = HW / PXB;     // 8
  constexpr int OPT = (PXB * COBW) / 256;
  static_assert(OPT * 256 == PXB * COBW, "combine exact");
  const float r15 = rsqrtf(1.0f + 1e-5f);

  __shared__ float scr[KS][COBW][PXB];   // [seg][j][px]: combine reads stride-1

  int tid = threadIdx.x;
  int wv = __builtin_amdgcn_readfirstlane(tid >> 6);
  int lane = tid & 63;
  int gb = blockIdx.x;
  int cg = gb / (Bc * NPG);
  int rem = gb % (Bc * NPG);
  int pg = rem % NPG;
  int b = rem / NPG;
  int co0 = cg * COBW;
  int px = pg * PXB + lane * 2;

  const float* xc = x + ((long)b * CIN + wv * CSEG) * HW + px;
  const float* wseg = w + wv * CSEG;     // + (co0+j)*CIN + c

  float acc[2][COBW];
#pragma unroll
  for (int p = 0; p < 2; ++p)
#pragma unroll
    for (int j = 0; j < COBW; ++j) acc[p][j] = 0.f;

#pragma unroll 4
  for (int c = 0; c < CSEG; ++c) {
    float2 v = *(const float2*)&xc[(long)c * HW];
#pragma unroll
    for (int j = 0; j < COBW; ++j) {
      float ww = wseg[(long)(co0 + j) * CIN + c];
      if (ISADD) {
        acc[0][j] += fabsf(v.x - ww);
        acc[1][j] += fabsf(v.y - ww);
      } else {
        acc[0][j] = fmaf(v.x, ww, acc[0][j]);
        acc[1][j] = fmaf(v.y, ww, acc[1][j]);
      }
    }
  }

  // partials -> LDS (per lane: float2 over p, stride 8B -> conflict-lite)
#pragma unroll
  for (int j = 0; j < COBW; ++j) {
    float2 t = make_float2(acc[0][j], acc[1][j]);
    *(float2*)&scr[wv][j][lane * 2] = t;
  }
  __syncthreads();

  // combine + epilogue: thread e -> (j = e/PXB, px = e%PXB); stride-1 reads
#pragma unroll
  for (int k = 0; k < OPT; ++k) {
    int e = k * 256 + tid;
    int pxl = e % PXB;
    int j = e / PXB;
    float s = scr[0][j][pxl] + scr[1][j][pxl] + scr[2][j][pxl] + scr[3][j][pxl];
    float val = ISADD ? -s : s + bias[co0 + j];
    long oidx = ((long)b * Dc + co0 + j) * HW + pg * PXB + pxl;
    if (EPI == 2) val = res[oidx] + val;
    if (EPI == 3) {
      float rg = rG[co0 + j] * r15, rbb = rB[co0 + j];
      val = fmaf(res[oidx], rg, rbb) + val;
    }
    if (EPI == 6) {
      float rg = rG[co0 + j] * r15, rbb = rB[co0 + j];
      float og = oG[co0 + j] * r15, obb = oB[co0 + j];
      val = fmaf(fmaf(res[oidx], rg, rbb) + val, og, obb);
    }
    out[oidx] = val;
  }
}

// ---------------------------------------------------------------------------
// R23: 2x bilinear upsample, paired-column form (FROZEN).
__device__ __forceinline__ void up_coef(int p, int H, int& i0, int& i1, float& w0, float& w1) {
  int m = p >> 1;
  if ((p & 1) == 0) { i0 = (m > 0) ? m - 1 : 0; i1 = m; w0 = 0.25f; w1 = 0.75f; }
  else              { i0 = m; i1 = (m + 1 < H) ? m + 1 : H - 1; w0 = 0.75f; w1 = 0.25f; }
}

__global__ void up2x2_kernel(const float* __restrict__ in, float* __restrict__ out,
                             int C, int H, int W) {
  int H2 = 2 * H, W2 = 2 * W;
  int i = blockIdx.x * blockDim.x + threadIdx.x;
  int total = Bc * C * H2 * W;           // one thread per (row, col-pair)
  if (i >= total) return;
  int t = i % W; int u = i / W;
  int oh = u % H2; u /= H2;
  int c = u % C; int b = u / C;
  int y0, y1; float wy0, wy1;
  up_coef(oh, H, y0, y1, wy0, wy1);
  const float* p = in + (b * C + c) * H * W;
  int xm1 = (t > 0) ? t - 1 : 0;
  int xp1 = (t + 1 < W) ? t + 1 : W - 1;
  float r0 = wy0 * p[y0 * W + xm1] + wy1 * p[y1 * W + xm1];
  float r1 = wy0 * p[y0 * W + t]   + wy1 * p[y1 * W + t];
  float r2 = wy0 * p[y0 * W + xp1] + wy1 * p[y1 * W + xp1];
  float2 o = make_float2(0.25f * r0 + 0.75f * r1, 0.75f * r1 + 0.25f * r2);
  *(float2*)&out[((long)(b * C + c) * H2 + oh) * W2 + 2 * t] = o;
}

// ---------------------------------------------------------------------------
// R23: up2x -> conv3x3(128->Cout) -> +bias -> tanh, CHANNEL-SPLIT x8 (FROZEN).
__global__ __launch_bounds__(256)
void conv3x3_up_tanh_ks(const float* __restrict__ x, const float* __restrict__ w,
                        const float* __restrict__ bias, float* __restrict__ out,
                        int Hs, int Ws, int Cout) {
  constexpr int CIN = Dc;
  constexpr int SEG = 8;            // channel segments (2 per wave)
  constexpr int CSEG = CIN / SEG;   // 16
  constexpr int QB = 32;            // quads per block
  __shared__ float scr[SEG][4][QB]; // 4KB

  int H2 = 2 * Hs, W2 = 2 * Ws;
  int nq = Hs * Ws;
  int tid = threadIdx.x;
  int q_l = tid % QB;               // quad slot within block
  int seg = tid / QB;               // 0..7
  int gq = blockIdx.x * QB + q_l;   // global quad: (b, co, m, n)
  int q = gq % nq; int t2 = gq / nq;
  int co = t2 % Cout; int b = t2 / Cout;
  int n = q % Ws, m = q / Ws;
  int rows[3] = { (m > 0) ? m - 1 : 0, m, (m + 1 < Hs) ? m + 1 : Hs - 1 };
  int cols[3] = { (n > 0) ? n - 1 : 0, n, (n + 1 < Ws) ? n + 1 : Ws - 1 };
  float rv[4] = { (2 * m - 1 >= 0) ? 1.f : 0.f, 1.f, 1.f, (2 * m + 2 < H2) ? 1.f : 0.f };
  float cv[4] = { (2 * n - 1 >= 0) ? 1.f : 0.f, 1.f, 1.f, (2 * n + 2 < W2) ? 1.f : 0.f };
  float acc[4] = { 0.f, 0.f, 0.f, 0.f };
  const float* xb = x + (b * CIN + seg * CSEG) * nq;
  const float* wb = w + (co * CIN + seg * CSEG) * 9;
  for (int c = 0; c < CSEG; ++c) {
    const float* xc = xb + c * nq;
    float s[3][3];
#pragma unroll
    for (int a = 0; a < 3; ++a)
#pragma unroll
      for (int e = 0; e < 3; ++e) s[a][e] = xc[rows[a] * Ws + cols[e]];
    float rb[4][3];
#pragma unroll
    for (int e = 0; e < 3; ++e) {
      rb[0][e] = fmaf(0.75f, s[0][e], 0.25f * s[1][e]);
      rb[1][e] = fmaf(0.25f, s[0][e], 0.75f * s[1][e]);
      rb[2][e] = fmaf(0.75f, s[1][e], 0.25f * s[2][e]);
      rb[3][e] = fmaf(0.25f, s[1][e], 0.75f * s[2][e]);
    }
    float u[4][4];
#pragma unroll
    for (int di = 0; di < 4; ++di) {
      float rm = rv[di];
      u[di][0] = fmaf(0.75f, rb[di][0], 0.25f * rb[di][1]) * rm * cv[0];
      u[di][1] = fmaf(0.25f, rb[di][0], 0.75f * rb[di][1]) * rm * cv[1];
      u[di][2] = fmaf(0.75f, rb[di][1], 0.25f * rb[di][2]) * rm * cv[2];
      u[di][3] = fmaf(0.25f, rb[di][1], 0.75f * rb[di][2]) * rm * cv[3];
    }
    const float* wc = wb + c * 9;
#pragma unroll
    for (int kh = 0; kh < 3; ++kh)
#pragma unroll
      for (int kw = 0; kw < 3; ++kw) {
        float ww = wc[kh * 3 + kw];
        acc[0] = fmaf(u[kh][kw],         ww, acc[0]);
        acc[1] = fmaf(u[kh][kw + 1],     ww, acc[1]);
        acc[2] = fmaf(u[kh + 1][kw],     ww, acc[2]);
        acc[3] = fmaf(u[kh + 1][kw + 1], ww, acc[3]);
      }
  }
#pragma unroll
  for (int di = 0; di < 4; ++di) scr[seg][di][q_l] = acc[di];
  __syncthreads();
  // write phase: threads 0..127 -> (quad q_l, sub-pixel di); stride-1 LDS
  if (tid < 4 * QB) {
    int ql2 = tid % QB;
    int di = tid / QB;
    int gq2 = blockIdx.x * QB + ql2;
    int q2 = gq2 % nq; int t3 = gq2 / nq;
    int co2 = t3 % Cout; int b2 = t3 / Cout;
    int n2 = q2 % Ws, m2 = q2 / Ws;
    float sum = bias[co2];
#pragma unroll
    for (int sg = 0; sg < SEG; ++sg) sum += scr[sg][di][ql2];
    out[(long)(b2 * Cout + co2) * H2 * W2 + (2 * m2 + (di >> 1)) * W2 + 2 * n2 + (di & 1)]
        = tanhf(sum);
  }
}

// ---------------------------------------------------------------------------
// R23: VQ nearest-embedding, 512 threads — one kk per thread (FROZEN).
__global__ __launch_bounds__(512)
void vq_kernel8(const float* __restrict__ z_e, const float* __restrict__ E,
                float* __restrict__ emb, float* __restrict__ argmin_out) {
  constexpr int HW = 1024;
  __shared__ alignas(16) float f[8][Dc];
  __shared__ float d2s[8][512];
  __shared__ int   ks[8][512];
  int tid = threadIdx.x;
  int n0 = blockIdx.x * 8;
  int b = n0 >> 10;
  int rem = n0 & 1023;
  const float* zb = z_e + (long)b * Dc * HW + rem;
#pragma unroll
  for (int i = 0; i < 2; ++i) {
    int e = i * 512 + tid;
    int p = e & 7, d = e >> 3;
    f[p][d] = zb[d * HW + p];
  }
  __syncthreads();
  float f2 = 0.f;
  if (tid < 8) {
    for (int d = 0; d < Dc; ++d) f2 += f[tid][d] * f[tid][d];
    d2s[tid][0] = f2;
  }
  __syncthreads();
  float f2v[8];
#pragma unroll
  for (int p = 0; p < 8; ++p) f2v[p] = d2s[p][0];
  __syncthreads();

  int kk = tid;                    // Kc == 512: one codebook entry per thread
  float dot[8];
#pragma unroll
  for (int p = 0; p < 8; ++p) dot[p] = 0.f;
  float e2k = 0.f;
  for (int d4 = 0; d4 < Dc; d4 += 4) {
    float e0 = E[(long)(d4 + 0) * Kc + kk];
    float e1 = E[(long)(d4 + 1) * Kc + kk];
    float e2c = E[(long)(d4 + 2) * Kc + kk];
    float e3 = E[(long)(d4 + 3) * Kc + kk];
    // same sequential d-ascending order as the separate e2 kernel
    e2k = fmaf(e0, e0, e2k);
    e2k = fmaf(e1, e1, e2k);
    e2k = fmaf(e2c, e2c, e2k);
    e2k = fmaf(e3, e3, e2k);
#pragma unroll
    for (int p = 0; p < 8; ++p) {
      float4 fv = *(const float4*)&f[p][d4];   // ds_read_b128 broadcast
      dot[p] = fmaf(fv.x, e0, dot[p]);
      dot[p] = fmaf(fv.y, e1, dot[p]);
      dot[p] = fmaf(fv.z, e2c, dot[p]);
      dot[p] = fmaf(fv.w, e3, dot[p]);
    }
  }
#pragma unroll
  for (int p = 0; p < 8; ++p) {
    d2s[p][tid] = f2v[p] - 2.f * dot[p] + e2k;
    ks[p][tid] = kk;
  }
  __syncthreads();
  for (int s = 256; s > 0; s >>= 1) {
    if (tid < s) {
#pragma unroll
      for (int p = 0; p < 8; ++p) {
        float ob = d2s[p][tid + s]; int ok = ks[p][tid + s];
        if (ob < d2s[p][tid] || (ob == d2s[p][tid] && ok < ks[p][tid])) {
          d2s[p][tid] = ob; ks[p][tid] = ok;
        }
      }
    }
    __syncthreads();
  }
  if (tid < 8) argmin_out[n0 + tid] = (float)ks[tid][0];
  float* eb = emb + (long)b * Dc * HW + rem;
#pragma unroll
  for (int i = 0; i < 2; ++i) {
    int e = i * 512 + tid;
    int p = e & 7, d = e >> 3;
    eb[d * HW + p] = E[d * Kc + ks[p][0]];
  }
}

// ---------------------------------------------------------------------------
extern "C" void kernel_launch(void* const* d_in, const int* in_sizes, int n_in,
                              void* d_out, int out_size, void* d_ws, size_t ws_size,
                              hipStream_t stream) {
  const float* x      = (const float*)d_in[0];
  const float* we1    = (const float*)d_in[1];
  const float* we2    = (const float*)d_in[2];
  const float* ae1_w1 = (const float*)d_in[3];
  const float* ae1_w2 = (const float*)d_in[4];
  const float* ae2_w1 = (const float*)d_in[5];
  const float* ae2_w2 = (const float*)d_in[6];
  const float* bn_g   = (const float*)d_in[7];   // [8,128]
  const float* bn_b   = (const float*)d_in[8];
  const float* embw   = (const float*)d_in[9];   // [128,512]
  const float* rd1_w1 = (const float*)d_in[10];
  const float* rd1_b1 = (const float*)d_in[11];
  const float* rd1_w2 = (const float*)d_in[12];
  const float* rd1_b2 = (const float*)d_in[13];
  const float* rd2_w1 = (const float*)d_in[14];
  const float* rd2_b1 = (const float*)d_in[15];
  const float* rd2_w2 = (const float*)d_in[16];
  const float* rd2_b2 = (const float*)d_in[17];
  const float* cd1_w  = (const float*)d_in[18];
  const float* cd1_b  = (const float*)d_in[19];
  const float* cd2_w  = (const float*)d_in[20];
  const float* cd2_b  = (const float*)d_in[21];

  const float* g0 = bn_g + 0 * Dc; const float* b0 = bn_b + 0 * Dc;
  const float* g1 = bn_g + 1 * Dc; const float* b1 = bn_b + 1 * Dc;
  const float* g2 = bn_g + 2 * Dc; const float* b2 = bn_b + 2 * Dc;
  const float* g3 = bn_g + 3 * Dc; const float* b3 = bn_b + 3 * Dc;
  const float* g4 = bn_g + 4 * Dc; const float* b4 = bn_b + 4 * Dc;
  const float* g5 = bn_g + 5 * Dc; const float* b5 = bn_b + 5 * Dc;
  const float* g6 = bn_g + 6 * Dc; const float* b6 = bn_b + 6 * Dc;
  const float* g7 = bn_g + 7 * Dc; const float* b7 = bn_b + 7 * Dc;

  // Workspace: two 64x64 buffers + three 32x32 buffers
  float* W64a = (float*)d_ws;            // [8,128,64,64]
  float* W64b = W64a + 4194304;          // [8,128,64,64]
  float* Wa   = W64b + 4194304;          // [8,128,32,32]
  float* Wb   = Wa + 1048576;
  float* Wc   = Wb + 1048576;

  // Output layout: y | z_e | emb | argmin
  float* out_y   = (float*)d_out;        // 8*3*128*128
  float* out_ze  = out_y  + 393216;      // 8*128*32*32
  float* out_emb = out_ze + 1048576;
  float* out_am  = out_emb + 1048576;

  const int TB = 256;
  auto nb = [](int n) { return (n + 255) / 256; };
  const float* nul = nullptr;

  // R24 grids: narrow 4-wave blocks, NCG = 128/(NWG*COBW) with NWG=2.
  const int G32n = 32 * Bc * 8;          // 2048 (32x32: NWG=2, COBW=2, NBAND=8)
  const int Gwe1 = 8 * Bc * 32;          // 2048 (we1: NW=4, COBW=4, 8 blk/CU)
  const int Gcd1 = 8 * Bc * 32;          // 2048 (cd1: NWG=2, COBW=8, NBAND=32)
  const int Gpw  = 32 * Bc * 8;          // 2048 (pw1x1: COBW=4 -> 32 cout-grps)
  const int Gct  = Bc * 3 * 64 * 64 / 32;// 3072 (conv3x3_up_tanh_ks)
  const int Gup  = nb(Bc * Dc * 64 * 32);// up2x2: one thread per (row, col-pair)

  // ---------------- encoder ----------------
  // we1: adder 4x4 s2, 3ch (single chunk), 128->64; epi relu(bn0)
  lds_layer<1,4,2,1, 0,1, 3,3, 2, 2,64,128,128,64, 4,4,1><<<Gwe1, TB, 0, stream>>>(
      x, we1, nul, nul, nul, nul, nul, nul, g0, b0, W64a);
  // we2: adder 4x4 s2, 64->32; epi relu(bn1) -> Wa
  // R24: NW=4, CH=4/grp (CHS=8, LDS 21.5KB, 7 blk/CU = 28-wave cap), 16 chunks
  lds_layer<1,4,2,1, 0,1, Dc,4, 2, 4,32,64,64,32, 2,4,2><<<G32n, TB, 0, stream>>>(
      W64a, we2, nul, nul, nul, nul, nul, nul, g1, b1, Wa);
  // ae1 3x3 (input >=0); epi relu(bn2) -> Wb
  // R24: NW=4, CH=8/grp (CHS=16, LDS 13.8KB x8 = 110KB, 32-wave cap), 8 chunks
  lds_layer<1,3,1,1, 0,1, Dc,8, 2, 4,32,32,32,32, 2,4,2><<<G32n, TB, 0, stream>>>(
      Wa, ae1_w1, nul, nul, nul, nul, nul, nul, g2, b2, Wb);
  // ae1 1x1 (streaming); epi Wa + val -> Wc
  pw1x1<1,2,4><<<Gpw, TB, 0, stream>>>(
      Wb, ae1_w2, nul, Wa, nul, nul, nul, nul, Wc);
  // ae2 3x3: input relu(bn3(Wc)); epi relu(bn4) -> Wb
  lds_layer<1,3,1,1, 2,1, Dc,8, 2, 4,32,32,32,32, 2,4,2><<<G32n, TB, 0, stream>>>(
      Wc, ae2_w1, nul, g3, b3, nul, nul, nul, g4, b4, Wb);
  // ae2 1x1 (streaming): epi bn5( bn3(Wc) + val ) -> out_ze
  pw1x1<1,6,4><<<Gpw, TB, 0, stream>>>(
      Wb, ae2_w2, nul, Wc, g3, b3, g5, b5, out_ze);

  // ---------------- VQ (512-thr, e2 fused) ----------------
  vq_kernel8<<<Bc * 1024 / 8, 512, 0, stream>>>(out_ze, embw, out_emb, out_am);

  // ---------------- decoder (z_q == emb numerically) ----------------
  // rd1 3x3: input relu(emb); epi relu(val) -> Wb
  lds_layer<0,3,1,1, 1,5, Dc,8, 2, 4,32,32,32,32, 2,4,2><<<G32n, TB, 0, stream>>>(
      out_emb, rd1_w1, rd1_b1, nul, nul, nul, nul, nul, nul, nul, Wb);
  // rd1 1x1 (streaming): epi emb + val -> Wa
  pw1x1<0,2,4><<<Gpw, TB, 0, stream>>>(
      Wb, rd1_w2, rd1_b2, out_emb, nul, nul, nul, nul, Wa);
  // rd2 3x3: input relu(bn6(Wa)); epi relu(val) -> Wb
  lds_layer<0,3,1,1, 2,5, Dc,8, 2, 4,32,32,32,32, 2,4,2><<<G32n, TB, 0, stream>>>(
      Wa, rd2_w1, rd2_b1, g6, b6, nul, nul, nul, nul, nul, Wb);
  // rd2 1x1 (streaming): epi bn6(Wa) + val -> Wc
  pw1x1<0,3,4><<<Gpw, TB, 0, stream>>>(
      Wb, rd2_w2, rd2_b2, Wa, g6, b6, nul, nul, Wc);

  up2x2_kernel<<<Gup, TB, 0, stream>>>(Wc, W64a, Dc, 32, 32);
  // cd1 3x3 (64x64): epi relu(bn7(val)) -> W64b
  // R24: NW=4, CH=8/grp (CHS=16, LDS 17.4KB x8 = 139KB, 32-wave cap), 8 chunks
  lds_layer<0,3,1,1, 0,1, Dc,8, 2, 2,64,64,64,64, 8,4,2><<<Gcd1, TB, 0, stream>>>(
      W64a, cd1_w, cd1_b, nul, nul, nul, nul, nul, g7, b7, W64b);

  // fused: up2x -> conv3x3(128->3) -> +bias -> tanh  (R23: channel-split x8)
  conv3x3_up_tanh_ks<<<Gct, TB, 0, stream>>>(W64b, cd2_w, cd2_b, out_y, 64, 64, 3);
}

// Round 13
// 779.717 us; speedup vs baseline: 1.0299x; 1.0299x over previous
//
#include <hip/hip_runtime.h>
#include <math.h>

// Problem constants
constexpr int Dc = 128;   // channels
constexpr int Kc = 512;   // codebook entries
constexpr int Bc = 8;     // batch

// ---------------------------------------------------------------------------
// LDS-tiled layer kernel: conv (ISADD=0) or AdderNet L1 (ISADD=1).
// Block = NW waves; KSPLIT wave-groups of NWG=NW/KSPLIT waves. Group g
// computes the block's couts over channels [g*CIN/KSPLIT, (g+1)*CIN/KSPLIT)
// at full COBW; partials combined via round-robin LDS scratch.
// CONFIG = R23 champion (783.2 us) — FINAL. Complete lever ledger (measured):
//   GOOD: K-split x2 (R16: 877->834); streaming 1x1 (R18); VQ e2-fuse (R21);
//   occupancy-split of latency-bound tails (R22: -45us); chl unroll-2 (R22).
//   DEAD: COBW growth (R17: marginal ~112 VALU/cout); PW growth (R19: +17us);
//   chunk growth (R20: LDS occupancy cap binds); dbuf single-barrier (R13:
//   busy 75->39); narrow 4-wave blocks (R24: +20us, occ 52->45, conflicts
//   +33% — the ~52% occupancy at 100% static cap is HW barrier-cadence
//   behavior, not block-geometry-recoverable).
// Terminal state: VALUBusy ~80%, FETCH ideal, conflicts structural. Remaining
// gap to useful-VALU floor is inner-loop instr mix (fragment loads+addressing
// ~1.2x useful) — five shape-space attacks all regressed; disasm-level only.
//
// IT: 0 none, 1 relu, 2 relu(bn) with itG/itB
// EPI (val = -acc adder / acc conv): 1 relu(bn_o(val)); 2 res+val;
//   3 bn_r(res)+val; 5 relu(val); 6 bn_o(bn_r(res)+val)
template<int ISADD, int K, int STRIDE, int PAD, int IT, int EPI, int CIN, int CH,
         int PW, int OUT_ROWS, int WOUT, int WIN, int HIN, int HOUT, int COBW,
         int NW, int KSPLIT>
__global__ __launch_bounds__(NW * 64)
void lds_layer(const float* __restrict__ x, const float* __restrict__ w,
               const float* __restrict__ bias,
               const float* __restrict__ itG, const float* __restrict__ itB,
               const float* __restrict__ res,
               const float* __restrict__ rG, const float* __restrict__ rB,
               const float* __restrict__ oG, const float* __restrict__ oB,
               float* __restrict__ out) {
  constexpr int BT = NW * 64;
  constexpr int NWG = NW / KSPLIT;            // waves per K-group
  constexpr int CINW = CIN / KSPLIT;          // channels per K-group
  constexpr int CHS = KSPLIT * CH;            // channels staged per chunk iter
  constexpr int KK = K * K;
  constexpr int SPAN = (PW - 1) * STRIDE + K;
  constexpr int IN_ROWS = (OUT_ROWS - 1) * STRIDE + K;
  constexpr int WPAD = (WOUT - 1) * STRIDE + K;
  constexpr int WLDS = (WPAD + 3) & ~3;       // mult of 4: aligned vector reads
  constexpr int PGW = WOUT / PW;
  static_assert(OUT_ROWS * PGW == 64, "one wave covers the pixel tile");
  static_assert(NW % KSPLIT == 0 && CIN % KSPLIT == 0 && CINW % CH == 0, "split");
  static_assert(KSPLIT == 1 ||
                NWG * 64 * PW * COBW <= CHS * IN_ROWS * WLDS, "scratch fits");
  constexpr int NBAND = HOUT / OUT_ROWS;
  constexpr int W4 = WIN / 4;
  constexpr int NELEM4 = CHS * IN_ROWS * W4;
  constexpr int NIT4 = (NELEM4 + BT - 1) / BT;
  constexpr bool EXACT = (NELEM4 % BT) == 0;
  const float r15 = rsqrtf(1.0f + 1e-5f);

  __shared__ alignas(16) float lds[CHS][IN_ROWS][WLDS];

  int tid = threadIdx.x;
  int gb = blockIdx.x;
  // XCD swizzle: cg outermost -> all channel-groups of a band share an XCD L2.
  int cg = gb / (Bc * NBAND);
  int rem = gb % (Bc * NBAND);
  int band = rem % NBAND;
  int b = rem / NBAND;
  int wv = __builtin_amdgcn_readfirstlane(tid >> 6);
  int lane = tid & 63;
  int grp = wv / NWG;                          // K-group of this wave
  int wloc = wv % NWG;
  int co0 = cg * (NWG * COBW) + wloc * COBW;
  int pr = lane / PGW, pc = lane % PGW;
  int oh = band * OUT_ROWS + pr;
  int ow0 = pc * PW;
  int yi0 = band * OUT_ROWS * STRIDE - PAD;

  // zero LDS once: pad columns stay zero forever
  for (int e = tid; e < CHS * IN_ROWS * WLDS; e += BT) ((float*)lds)[e] = 0.f;

  float acc[PW][COBW];
#pragma unroll
  for (int p = 0; p < PW; ++p)
#pragma unroll
    for (int j = 0; j < COBW; ++j)
      acc[p][j] = (ISADD || grp != 0) ? 0.f : bias[co0 + j];

  const float* xb = x + (long)b * CIN * HIN * WIN;
  float4 rbuf[NIT4];

  // stage chunk cc: tile channel ch2 (<CHS) <- global channel
  //   gc = cc + (ch2 % CH) + (ch2 / CH) * CINW   (group-interleaved slices)
  auto stage = [&](int cc) {
#pragma unroll
    for (int it = 0; it < NIT4; ++it) {
      int e = it * BT + tid;
      if (!EXACT && e >= NELEM4) break;
      int c4 = e % W4;
      int r = (e / W4) % IN_ROWS;
      int ch2 = e / (W4 * IN_ROWS);
      int gc = cc + (ch2 % CH) + (ch2 / CH) * CINW;
      int yi = yi0 + r;
      float4 v = make_float4(0.f, 0.f, 0.f, 0.f);
      if (yi >= 0 && yi < HIN) {
        v = *(const float4*)&xb[((long)gc * HIN + yi) * WIN + 4 * c4];
        if (IT == 1) {
          v.x = fmaxf(v.x, 0.f); v.y = fmaxf(v.y, 0.f);
          v.z = fmaxf(v.z, 0.f); v.w = fmaxf(v.w, 0.f);
        }
        if (IT == 2) {
          float sc = itG[gc] * r15, bc = itB[gc];
          v.x = fmaxf(fmaf(v.x, sc, bc), 0.f);
          v.y = fmaxf(fmaf(v.y, sc, bc), 0.f);
          v.z = fmaxf(fmaf(v.z, sc, bc), 0.f);
          v.w = fmaxf(fmaf(v.w, sc, bc), 0.f);
        }
      }
      rbuf[it] = v;
    }
  };
  auto towrite = [&]() {
#pragma unroll
    for (int it = 0; it < NIT4; ++it) {
      int e = it * BT + tid;
      if (!EXACT && e >= NELEM4) break;
      int c4 = e % W4;
      int r = (e / W4) % IN_ROWS;
      int ch2 = e / (W4 * IN_ROWS);
      float* p = &lds[ch2][r][4 * c4 + PAD];
      float4 v = rbuf[it];
      p[0] = v.x; p[1] = v.y; p[2] = v.z; p[3] = v.w;
    }
  };

  stage(0);
  for (int cc = 0; cc < CINW; cc += CH) {
    __syncthreads();           // previous compute done before LDS overwrite
    towrite();
    __syncthreads();           // all writes visible
    if (cc + CH < CINW) stage(cc + CH);   // loads overlap compute below
#pragma unroll 2
    for (int chl = 0; chl < CH; ++chl) {
      float vbuf[K][SPAN];
#pragma unroll
      for (int kh = 0; kh < K; ++kh) {
        const float* rp0 = &lds[grp * CH + chl][pr * STRIDE + kh][ow0 * STRIDE];
        if constexpr (SPAN == 6 && (PW * STRIDE) % 4 == 0) {
          float4 a = *(const float4*)rp0;            // 16B aligned: col=4*pc
          float2 c2 = *(const float2*)(rp0 + 4);
          vbuf[kh][0] = a.x; vbuf[kh][1] = a.y; vbuf[kh][2] = a.z;
          vbuf[kh][3] = a.w; vbuf[kh][4] = c2.x; vbuf[kh][5] = c2.y;
        } else if constexpr (SPAN == 4 && (PW * STRIDE) % 2 == 0) {
          float2 a = *(const float2*)rp0;            // 8B aligned: col=2*pc
          float2 c2 = *(const float2*)(rp0 + 2);
          vbuf[kh][0] = a.x; vbuf[kh][1] = a.y;
          vbuf[kh][2] = c2.x; vbuf[kh][3] = c2.y;
        } else if constexpr (SPAN == 2 && (PW * STRIDE) % 2 == 0) {
          float2 a = *(const float2*)rp0;
          vbuf[kh][0] = a.x; vbuf[kh][1] = a.y;
        } else {
#pragma unroll
          for (int s = 0; s < SPAN; ++s) vbuf[kh][s] = rp0[s];
        }
      }
      const float* wc = w + ((long)co0 * CIN + (grp * CINW + cc + chl)) * KK;
#pragma unroll
      for (int kh = 0; kh < K; ++kh)
#pragma unroll
        for (int kw = 0; kw < K; ++kw)
#pragma unroll
          for (int j = 0; j < COBW; ++j) {
            float ww = wc[(long)j * CIN * KK + kh * K + kw];
#pragma unroll
            for (int p = 0; p < PW; ++p) {
              float v = vbuf[kh][p * STRIDE + kw];
              if (ISADD) acc[p][j] += fabsf(v - ww);
              else       acc[p][j] = fmaf(v, ww, acc[p][j]);
            }
          }
    }
  }

  // ---- K-split combine: round-robin, group g -> group 0 via LDS scratch ----
  if constexpr (KSPLIT >= 2) {
    float* scr = (float*)lds;
    int sb = (wloc * 64 + lane) * (PW * COBW);
#pragma unroll
    for (int g = 1; g < KSPLIT; ++g) {
      __syncthreads();                     // tile/scratch dead or consumed
      if (grp == g) {
#pragma unroll
        for (int p = 0; p < PW; ++p)
#pragma unroll
          for (int j = 0; j < COBW; ++j) scr[sb + p * COBW + j] = acc[p][j];
      }
      __syncthreads();
      if (grp == 0) {
#pragma unroll
        for (int p = 0; p < PW; ++p)
#pragma unroll
          for (int j = 0; j < COBW; ++j) acc[p][j] += scr[sb + p * COBW + j];
      }
    }
    if (grp != 0) return;                  // non-root groups done
  }

  // ---- epilogue ----
  long obase = ((long)(b * Dc + co0) * HOUT + oh) * WOUT + ow0;
  float* ob = out + obase;
  const float* rp = (EPI == 2 || EPI == 3 || EPI == 6) ? res + obase : nullptr;
  constexpr long hw = (long)HOUT * WOUT;
#pragma unroll
  for (int j = 0; j < COBW; ++j) {
    float og = 0.f, obb = 0.f, rg = 0.f, rbb = 0.f;
    if (EPI == 1 || EPI == 6) { og = oG[co0 + j] * r15; obb = oB[co0 + j]; }
    if (EPI == 3 || EPI == 6) { rg = rG[co0 + j] * r15; rbb = rB[co0 + j]; }
#pragma unroll
    for (int p = 0; p < PW; ++p) {
      float val = ISADD ? -acc[p][j] : acc[p][j];
      if (EPI == 1) val = fmaxf(fmaf(val, og, obb), 0.f);
      if (EPI == 2) val = rp[j * hw + p] + val;
      if (EPI == 3) val = fmaf(rp[j * hw + p], rg, rbb) + val;
      if (EPI == 5) val = fmaxf(val, 0.f);
      if (EPI == 6) val = fmaf(fmaf(rp[j * hw + p], rg, rbb) + val, og, obb);
      ob[j * hw + p] = val;
    }
  }
}

// ---------------------------------------------------------------------------
// R18: streaming 1x1 layer — no staging LDS, no chunk barriers (FROZEN).
template<int ISADD, int EPI, int COBW>
__global__ __launch_bounds__(256)
void pw1x1(const float* __restrict__ x, const float* __restrict__ w,
           const float* __restrict__ bias,
           const float* __restrict__ res,
           const float* __restrict__ rG, const float* __restrict__ rB,
           const float* __restrict__ oG, const float* __restrict__ oB,
           float* __restrict__ out) {
  constexpr int HW = 1024;          // 32x32
  constexpr int CIN = Dc;
  constexpr int KS = 4;             // waves per block = channel segments
  constexpr int CSEG = CIN / KS;    // 32
  constexpr int PXB = 128;          // pixels per block (2 per lane)
  constexpr int NPG = HW / PXB;     // 8
  constexpr int OPT = (PXB * COBW) / 256;
  static_assert(OPT * 256 == PXB * COBW, "combine exact");
  const float r15 = rsqrtf(1.0f + 1e-5f);

  __shared__ float scr[KS][COBW][PXB];   // [seg][j][px]: combine reads stride-1

  int tid = threadIdx.x;
  int wv = __builtin_amdgcn_readfirstlane(tid >> 6);
  int lane = tid & 63;
  int gb = blockIdx.x;
  int cg = gb / (Bc * NPG);
  int rem = gb % (Bc * NPG);
  int pg = rem % NPG;
  int b = rem / NPG;
  int co0 = cg * COBW;
  int px = pg * PXB + lane * 2;

  const float* xc = x + ((long)b * CIN + wv * CSEG) * HW + px;
  const float* wseg = w + wv * CSEG;     // + (co0+j)*CIN + c

  float acc[2][COBW];
#pragma unroll
  for (int p = 0; p < 2; ++p)
#pragma unroll
    for (int j = 0; j < COBW; ++j) acc[p][j] = 0.f;

#pragma unroll 4
  for (int c = 0; c < CSEG; ++c) {
    float2 v = *(const float2*)&xc[(long)c * HW];
#pragma unroll
    for (int j = 0; j < COBW; ++j) {
      float ww = wseg[(long)(co0 + j) * CIN + c];
      if (ISADD) {
        acc[0][j] += fabsf(v.x - ww);
        acc[1][j] += fabsf(v.y - ww);
      } else {
        acc[0][j] = fmaf(v.x, ww, acc[0][j]);
        acc[1][j] = fmaf(v.y, ww, acc[1][j]);
      }
    }
  }

  // partials -> LDS (per lane: float2 over p, stride 8B -> conflict-lite)
#pragma unroll
  for (int j = 0; j < COBW; ++j) {
    float2 t = make_float2(acc[0][j], acc[1][j]);
    *(float2*)&scr[wv][j][lane * 2] = t;
  }
  __syncthreads();

  // combine + epilogue: thread e -> (j = e/PXB, px = e%PXB); stride-1 reads
#pragma unroll
  for (int k = 0; k < OPT; ++k) {
    int e = k * 256 + tid;
    int pxl = e % PXB;
    int j = e / PXB;
    float s = scr[0][j][pxl] + scr[1][j][pxl] + scr[2][j][pxl] + scr[3][j][pxl];
    float val = ISADD ? -s : s + bias[co0 + j];
    long oidx = ((long)b * Dc + co0 + j) * HW + pg * PXB + pxl;
    if (EPI == 2) val = res[oidx] + val;
    if (EPI == 3) {
      float rg = rG[co0 + j] * r15, rbb = rB[co0 + j];
      val = fmaf(res[oidx], rg, rbb) + val;
    }
    if (EPI == 6) {
      float rg = rG[co0 + j] * r15, rbb = rB[co0 + j];
      float og = oG[co0 + j] * r15, obb = oB[co0 + j];
      val = fmaf(fmaf(res[oidx], rg, rbb) + val, og, obb);
    }
    out[oidx] = val;
  }
}

// ---------------------------------------------------------------------------
// R23: 2x bilinear upsample, paired-column form (FROZEN).
__device__ __forceinline__ void up_coef(int p, int H, int& i0, int& i1, float& w0, float& w1) {
  int m = p >> 1;
  if ((p & 1) == 0) { i0 = (m > 0) ? m - 1 : 0; i1 = m; w0 = 0.25f; w1 = 0.75f; }
  else              { i0 = m; i1 = (m + 1 < H) ? m + 1 : H - 1; w0 = 0.75f; w1 = 0.25f; }
}

__global__ void up2x2_kernel(const float* __restrict__ in, float* __restrict__ out,
                             int C, int H, int W) {
  int H2 = 2 * H, W2 = 2 * W;
  int i = blockIdx.x * blockDim.x + threadIdx.x;
  int total = Bc * C * H2 * W;           // one thread per (row, col-pair)
  if (i >= total) return;
  int t = i % W; int u = i / W;
  int oh = u % H2; u /= H2;
  int c = u % C; int b = u / C;
  int y0, y1; float wy0, wy1;
  up_coef(oh, H, y0, y1, wy0, wy1);
  const float* p = in + (b * C + c) * H * W;
  int xm1 = (t > 0) ? t - 1 : 0;
  int xp1 = (t + 1 < W) ? t + 1 : W - 1;
  float r0 = wy0 * p[y0 * W + xm1] + wy1 * p[y1 * W + xm1];
  float r1 = wy0 * p[y0 * W + t]   + wy1 * p[y1 * W + t];
  float r2 = wy0 * p[y0 * W + xp1] + wy1 * p[y1 * W + xp1];
  float2 o = make_float2(0.25f * r0 + 0.75f * r1, 0.75f * r1 + 0.25f * r2);
  *(float2*)&out[((long)(b * C + c) * H2 + oh) * W2 + 2 * t] = o;
}

// ---------------------------------------------------------------------------
// R23: up2x -> conv3x3(128->Cout) -> +bias -> tanh, CHANNEL-SPLIT x8 (FROZEN).
__global__ __launch_bounds__(256)
void conv3x3_up_tanh_ks(const float* __restrict__ x, const float* __restrict__ w,
                        const float* __restrict__ bias, float* __restrict__ out,
                        int Hs, int Ws, int Cout) {
  constexpr int CIN = Dc;
  constexpr int SEG = 8;            // channel segments (2 per wave)
  constexpr int CSEG = CIN / SEG;   // 16
  constexpr int QB = 32;            // quads per block
  __shared__ float scr[SEG][4][QB]; // 4KB

  int H2 = 2 * Hs, W2 = 2 * Ws;
  int nq = Hs * Ws;
  int tid = threadIdx.x;
  int q_l = tid % QB;               // quad slot within block
  int seg = tid / QB;               // 0..7
  int gq = blockIdx.x * QB + q_l;   // global quad: (b, co, m, n)
  int q = gq % nq; int t2 = gq / nq;
  int co = t2 % Cout; int b = t2 / Cout;
  int n = q % Ws, m = q / Ws;
  int rows[3] = { (m > 0) ? m - 1 : 0, m, (m + 1 < Hs) ? m + 1 : Hs - 1 };
  int cols[3] = { (n > 0) ? n - 1 : 0, n, (n + 1 < Ws) ? n + 1 : Ws - 1 };
  float rv[4] = { (2 * m - 1 >= 0) ? 1.f : 0.f, 1.f, 1.f, (2 * m + 2 < H2) ? 1.f : 0.f };
  float cv[4] = { (2 * n - 1 >= 0) ? 1.f : 0.f, 1.f, 1.f, (2 * n + 2 < W2) ? 1.f : 0.f };
  float acc[4] = { 0.f, 0.f, 0.f, 0.f };
  const float* xb = x + (b * CIN + seg * CSEG) * nq;
  const float* wb = w + (co * CIN + seg * CSEG) * 9;
  for (int c = 0; c < CSEG; ++c) {
    const float* xc = xb + c * nq;
    float s[3][3];
#pragma unroll
    for (int a = 0; a < 3; ++a)
#pragma unroll
      for (int e = 0; e < 3; ++e) s[a][e] = xc[rows[a] * Ws + cols[e]];
    float rb[4][3];
#pragma unroll
    for (int e = 0; e < 3; ++e) {
      rb[0][e] = fmaf(0.75f, s[0][e], 0.25f * s[1][e]);
      rb[1][e] = fmaf(0.25f, s[0][e], 0.75f * s[1][e]);
      rb[2][e] = fmaf(0.75f, s[1][e], 0.25f * s[2][e]);
      rb[3][e] = fmaf(0.25f, s[1][e], 0.75f * s[2][e]);
    }
    float u[4][4];
#pragma unroll
    for (int di = 0; di < 4; ++di) {
      float rm = rv[di];
      u[di][0] = fmaf(0.75f, rb[di][0], 0.25f * rb[di][1]) * rm * cv[0];
      u[di][1] = fmaf(0.25f, rb[di][0], 0.75f * rb[di][1]) * rm * cv[1];
      u[di][2] = fmaf(0.75f, rb[di][1], 0.25f * rb[di][2]) * rm * cv[2];
      u[di][3] = fmaf(0.25f, rb[di][1], 0.75f * rb[di][2]) * rm * cv[3];
    }
    const float* wc = wb + c * 9;
#pragma unroll
    for (int kh = 0; kh < 3; ++kh)
#pragma unroll
      for (int kw = 0; kw < 3; ++kw) {
        float ww = wc[kh * 3 + kw];
        acc[0] = fmaf(u[kh][kw],         ww, acc[0]);
        acc[1] = fmaf(u[kh][kw + 1],     ww, acc[1]);
        acc[2] = fmaf(u[kh + 1][kw],     ww, acc[2]);
        acc[3] = fmaf(u[kh + 1][kw + 1], ww, acc[3]);
      }
  }
#pragma unroll
  for (int di = 0; di < 4; ++di) scr[seg][di][q_l] = acc[di];
  __syncthreads();
  // write phase: threads 0..127 -> (quad q_l, sub-pixel di); stride-1 LDS
  if (tid < 4 * QB) {
    int ql2 = tid % QB;
    int di = tid / QB;
    int gq2 = blockIdx.x * QB + ql2;
    int q2 = gq2 % nq; int t3 = gq2 / nq;
    int co2 = t3 % Cout; int b2 = t3 / Cout;
    int n2 = q2 % Ws, m2 = q2 / Ws;
    float sum = bias[co2];
#pragma unroll
    for (int sg = 0; sg < SEG; ++sg) sum += scr[sg][di][ql2];
    out[(long)(b2 * Cout + co2) * H2 * W2 + (2 * m2 + (di >> 1)) * W2 + 2 * n2 + (di & 1)]
        = tanhf(sum);
  }
}

// ---------------------------------------------------------------------------
// R23: VQ nearest-embedding, 512 threads — one kk per thread (FROZEN).
__global__ __launch_bounds__(512)
void vq_kernel8(const float* __restrict__ z_e, const float* __restrict__ E,
                float* __restrict__ emb, float* __restrict__ argmin_out) {
  constexpr int HW = 1024;
  __shared__ alignas(16) float f[8][Dc];
  __shared__ float d2s[8][512];
  __shared__ int   ks[8][512];
  int tid = threadIdx.x;
  int n0 = blockIdx.x * 8;
  int b = n0 >> 10;
  int rem = n0 & 1023;
  const float* zb = z_e + (long)b * Dc * HW + rem;
#pragma unroll
  for (int i = 0; i < 2; ++i) {
    int e = i * 512 + tid;
    int p = e & 7, d = e >> 3;
    f[p][d] = zb[d * HW + p];
  }
  __syncthreads();
  float f2 = 0.f;
  if (tid < 8) {
    for (int d = 0; d < Dc; ++d) f2 += f[tid][d] * f[tid][d];
    d2s[tid][0] = f2;
  }
  __syncthreads();
  float f2v[8];
#pragma unroll
  for (int p = 0; p < 8; ++p) f2v[p] = d2s[p][0];
  __syncthreads();

  int kk = tid;                    // Kc == 512: one codebook entry per thread
  float dot[8];
#pragma unroll
  for (int p = 0; p < 8; ++p) dot[p] = 0.f;
  float e2k = 0.f;
  for (int d4 = 0; d4 < Dc; d4 += 4) {
    float e0 = E[(long)(d4 + 0) * Kc + kk];
    float e1 = E[(long)(d4 + 1) * Kc + kk];
    float e2c = E[(long)(d4 + 2) * Kc + kk];
    float e3 = E[(long)(d4 + 3) * Kc + kk];
    // same sequential d-ascending order as the separate e2 kernel
    e2k = fmaf(e0, e0, e2k);
    e2k = fmaf(e1, e1, e2k);
    e2k = fmaf(e2c, e2c, e2k);
    e2k = fmaf(e3, e3, e2k);
#pragma unroll
    for (int p = 0; p < 8; ++p) {
      float4 fv = *(const float4*)&f[p][d4];   // ds_read_b128 broadcast
      dot[p] = fmaf(fv.x, e0, dot[p]);
      dot[p] = fmaf(fv.y, e1, dot[p]);
      dot[p] = fmaf(fv.z, e2c, dot[p]);
      dot[p] = fmaf(fv.w, e3, dot[p]);
    }
  }
#pragma unroll
  for (int p = 0; p < 8; ++p) {
    d2s[p][tid] = f2v[p] - 2.f * dot[p] + e2k;
    ks[p][tid] = kk;
  }
  __syncthreads();
  for (int s = 256; s > 0; s >>= 1) {
    if (tid < s) {
#pragma unroll
      for (int p = 0; p < 8; ++p) {
        float ob = d2s[p][tid + s]; int ok = ks[p][tid + s];
        if (ob < d2s[p][tid] || (ob == d2s[p][tid] && ok < ks[p][tid])) {
          d2s[p][tid] = ob; ks[p][tid] = ok;
        }
      }
    }
    __syncthreads();
  }
  if (tid < 8) argmin_out[n0 + tid] = (float)ks[tid][0];
  float* eb = emb + (long)b * Dc * HW + rem;
#pragma unroll
  for (int i = 0; i < 2; ++i) {
    int e = i * 512 + tid;
    int p = e & 7, d = e >> 3;
    eb[d * HW + p] = E[d * Kc + ks[p][0]];
  }
}

// ---------------------------------------------------------------------------
extern "C" void kernel_launch(void* const* d_in, const int* in_sizes, int n_in,
                              void* d_out, int out_size, void* d_ws, size_t ws_size,
                              hipStream_t stream) {
  const float* x      = (const float*)d_in[0];
  const float* we1    = (const float*)d_in[1];
  const float* we2    = (const float*)d_in[2];
  const float* ae1_w1 = (const float*)d_in[3];
  const float* ae1_w2 = (const float*)d_in[4];
  const float* ae2_w1 = (const float*)d_in[5];
  const float* ae2_w2 = (const float*)d_in[6];
  const float* bn_g   = (const float*)d_in[7];   // [8,128]
  const float* bn_b   = (const float*)d_in[8];
  const float* embw   = (const float*)d_in[9];   // [128,512]
  const float* rd1_w1 = (const float*)d_in[10];
  const float* rd1_b1 = (const float*)d_in[11];
  const float* rd1_w2 = (const float*)d_in[12];
  const float* rd1_b2 = (const float*)d_in[13];
  const float* rd2_w1 = (const float*)d_in[14];
  const float* rd2_b1 = (const float*)d_in[15];
  const float* rd2_w2 = (const float*)d_in[16];
  const float* rd2_b2 = (const float*)d_in[17];
  const float* cd1_w  = (const float*)d_in[18];
  const float* cd1_b  = (const float*)d_in[19];
  const float* cd2_w  = (const float*)d_in[20];
  const float* cd2_b  = (const float*)d_in[21];

  const float* g0 = bn_g + 0 * Dc; const float* b0 = bn_b + 0 * Dc;
  const float* g1 = bn_g + 1 * Dc; const float* b1 = bn_b + 1 * Dc;
  const float* g2 = bn_g + 2 * Dc; const float* b2 = bn_b + 2 * Dc;
  const float* g3 = bn_g + 3 * Dc; const float* b3 = bn_b + 3 * Dc;
  const float* g4 = bn_g + 4 * Dc; const float* b4 = bn_b + 4 * Dc;
  const float* g5 = bn_g + 5 * Dc; const float* b5 = bn_b + 5 * Dc;
  const float* g6 = bn_g + 6 * Dc; const float* b6 = bn_b + 6 * Dc;
  const float* g7 = bn_g + 7 * Dc; const float* b7 = bn_b + 7 * Dc;

  // Workspace: two 64x64 buffers + three 32x32 buffers
  float* W64a = (float*)d_ws;            // [8,128,64,64]
  float* W64b = W64a + 4194304;          // [8,128,64,64]
  float* Wa   = W64b + 4194304;          // [8,128,32,32]
  float* Wb   = Wa + 1048576;
  float* Wc   = Wb + 1048576;

  // Output layout: y | z_e | emb | argmin
  float* out_y   = (float*)d_out;        // 8*3*128*128
  float* out_ze  = out_y  + 393216;      // 8*128*32*32
  float* out_emb = out_ze + 1048576;
  float* out_am  = out_emb + 1048576;

  const int TB = 256;
  const int TB8 = 512;
  auto nb = [](int n) { return (n + 255) / 256; };
  const float* nul = nullptr;

  // grids (R23 champion): NCG * Bc * NBAND, NCG = 128/(NWG*COBW).
  const int G32s = 16 * Bc * 8;          // 1024 (32x32: NWG=4, COBW=2, NBAND=8)
  const int Gwe1 = 8 * Bc * 32;          // 2048 (we1: NW=4, COBW=4, 8 blk/CU)
  const int Gcd1 = 4 * Bc * 32;          // 1024 (cd1: NWG=4, COBW=8, KSPLIT=2)
  const int Gpw  = 32 * Bc * 8;          // 2048 (pw1x1: COBW=4 -> 32 cout-grps)
  const int Gct  = Bc * 3 * 64 * 64 / 32;// 3072 (conv3x3_up_tanh_ks: 32 quads/blk)
  const int Gup  = nb(Bc * Dc * 64 * 32);// up2x2: one thread per (row, col-pair)

  // ---------------- encoder ----------------
  // we1: adder 4x4 s2, 3ch (single chunk), 128->64; epi relu(bn0)
  lds_layer<1,4,2,1, 0,1, 3,3, 2, 2,64,128,128,64, 4,4,1><<<Gwe1, TB, 0, stream>>>(
      x, we1, nul, nul, nul, nul, nul, nul, g0, b0, W64a);
  // we2: adder 4x4 s2, 64->32; epi relu(bn1) -> Wa  (R18: CH=4/grp, LDS 21.8KB)
  lds_layer<1,4,2,1, 0,1, Dc,4, 2, 4,32,64,64,32, 2,8,2><<<G32s, TB8, 0, stream>>>(
      W64a, we2, nul, nul, nul, nul, nul, nul, g1, b1, Wa);
  // ae1 3x3 (input >=0); epi relu(bn2) -> Wb  (R18: CH=16/grp, LDS 27.6KB)
  lds_layer<1,3,1,1, 0,1, Dc,16, 2, 4,32,32,32,32, 2,8,2><<<G32s, TB8, 0, stream>>>(
      Wa, ae1_w1, nul, nul, nul, nul, nul, nul, g2, b2, Wb);
  // ae1 1x1 (streaming); epi Wa + val -> Wc
  pw1x1<1,2,4><<<Gpw, TB, 0, stream>>>(
      Wb, ae1_w2, nul, Wa, nul, nul, nul, nul, Wc);
  // ae2 3x3: input relu(bn3(Wc)); epi relu(bn4) -> Wb
  lds_layer<1,3,1,1, 2,1, Dc,16, 2, 4,32,32,32,32, 2,8,2><<<G32s, TB8, 0, stream>>>(
      Wc, ae2_w1, nul, g3, b3, nul, nul, nul, g4, b4, Wb);
  // ae2 1x1 (streaming): epi bn5( bn3(Wc) + val ) -> out_ze
  pw1x1<1,6,4><<<Gpw, TB, 0, stream>>>(
      Wb, ae2_w2, nul, Wc, g3, b3, g5, b5, out_ze);

  // ---------------- VQ (512-thr, e2 fused) ----------------
  vq_kernel8<<<Bc * 1024 / 8, 512, 0, stream>>>(out_ze, embw, out_emb, out_am);

  // ---------------- decoder (z_q == emb numerically) ----------------
  // rd1 3x3: input relu(emb); epi relu(val) -> Wb
  lds_layer<0,3,1,1, 1,5, Dc,16, 2, 4,32,32,32,32, 2,8,2><<<G32s, TB8, 0, stream>>>(
      out_emb, rd1_w1, rd1_b1, nul, nul, nul, nul, nul, nul, nul, Wb);
  // rd1 1x1 (streaming): epi emb + val -> Wa
  pw1x1<0,2,4><<<Gpw, TB, 0, stream>>>(
      Wb, rd1_w2, rd1_b2, out_emb, nul, nul, nul, nul, Wa);
  // rd2 3x3: input relu(bn6(Wa)); epi relu(val) -> Wb
  lds_layer<0,3,1,1, 2,5, Dc,16, 2, 4,32,32,32,32, 2,8,2><<<G32s, TB8, 0, stream>>>(
      Wa, rd2_w1, rd2_b1, g6, b6, nul, nul, nul, nul, nul, Wb);
  // rd2 1x1 (streaming): epi bn6(Wa) + val -> Wc
  pw1x1<0,3,4><<<Gpw, TB, 0, stream>>>(
      Wb, rd2_w2, rd2_b2, Wa, g6, b6, nul, nul, Wc);

  up2x2_kernel<<<Gup, TB, 0, stream>>>(Wc, W64a, Dc, 32, 32);
  // cd1 3x3 (64x64): epi relu(bn7(val)) -> W64b  (R18: CH=8/grp, LDS 17.4KB)
  lds_layer<0,3,1,1, 0,1, Dc,8, 2, 2,64,64,64,64, 8,8,2><<<Gcd1, TB8, 0, stream>>>(
      W64a, cd1_w, cd1_b, nul, nul, nul, nul, nul, g7, b7, W64b);

  // fused: up2x -> conv3x3(128->3) -> +bias -> tanh  (R23: channel-split x8)
  conv3x3_up_tanh_ks<<<Gct, TB, 0, stream>>>(W64b, cd2_w, cd2_b, out_y, 64, 64, 3);
}